// Round 1
// baseline (214.844 us; speedup 1.0000x reference)
//
#include <hip/hip_runtime.h>

// ---------------------------------------------------------------------------
// Head_87033217286245: Conv1d(1024->64,k=3) + span-softmax extractor + MLP
// Design: f16-MFMA conv GEMM (HBM-bound, ~43us floor), tiny fp32 epilogue.
// ---------------------------------------------------------------------------

typedef _Float16 f16x8 __attribute__((ext_vector_type(8)));
typedef _Float16 f16x4 __attribute__((ext_vector_type(4)));
typedef float    f32x4 __attribute__((ext_vector_type(4)));

#define B_      128
#define L_      512
#define DBERT   1024
#define DPROJ   64
#define NSPANS  3
#define HIDDEN  512
#define KSTEPS  32          // 1024 / 32
#define APAD    40          // padded f16 cols per LDS row (80B stride: 2-way bank alias = free)

// packed weights: [kb 0..31][t 0..2][nf 0..3][lane 0..63][j 0..7] f16
// element = W[k = kb*32 + (lane>>4)*8 + j][o = nf*16 + (lane&15)] for tap t
// = 6144 f16 (12288 B) per kb step; total 393216 B.
__global__ __launch_bounds__(256)
void pack_w_kernel(const float* __restrict__ Wc, _Float16* __restrict__ Bp) {
    int idx = blockIdx.x * 256 + threadIdx.x;         // 24576 threads
    if (idx >= 32 * 3 * 4 * 64) return;
    int lane = idx & 63;
    int rest = idx >> 6;
    int nf   = rest & 3;
    int r2   = rest >> 2;
    int t    = r2 % 3;
    int kb   = r2 / 3;
    int o     = nf * 16 + (lane & 15);
    int kbase = kb * 32 + ((lane >> 4) << 3);
    f16x8 v;
    #pragma unroll
    for (int j = 0; j < 8; ++j)
        v[j] = (_Float16)Wc[(size_t)o * (DBERT * 3) + (size_t)(kbase + j) * 3 + t];
    *(f16x8*)(Bp + (size_t)idx * 8) = v;
}

// GEMM: conv_out[row, o] = sum_{t,k} X[row + t - 1 (in-batch), k] * W[o,k,t] + cb[o]
// Grid: 512 blocks (BM=128 rows each, never straddling a batch). 4 waves,
// wave w owns rows [32w, 32w+32) x all 64 cols. Taps = +0/+1/+2 row shift in
// the staged 130-row A tile.
__global__ __launch_bounds__(256, 2)
void conv_gemm_kernel(const float* __restrict__ X, const _Float16* __restrict__ Bp,
                      const float* __restrict__ cb, float* __restrict__ Y) {
    __shared__ __align__(16) _Float16 As[2][130 * APAD];
    __shared__ __align__(16) _Float16 Bs[2][6144];

    const int tid  = threadIdx.x;
    const int wv   = tid >> 6;
    const int lane = tid & 63;
    const int m0   = blockIdx.x * 128;
    const int l0   = m0 & (L_ - 1);
    const int g0   = m0 - l0;                         // batch base row

    const f32x4 vzero = {0.f, 0.f, 0.f, 0.f};
    f32x4 acc[2][4];
    #pragma unroll
    for (int a = 0; a < 2; ++a)
        #pragma unroll
        for (int b = 0; b < 4; ++b) acc[a][b] = vzero;

    // ---- prologue: stage kb=0 into buffer 0
    {
        #pragma unroll
        for (int it = 0; it < 4; ++it) {
            int q = tid + it * 256;                   // 1040 chunks = 130 rows x 8 float4
            int r = q >> 3, c4 = q & 7;
            int l = l0 - 1 + r;
            float4 v = make_float4(0.f, 0.f, 0.f, 0.f);
            if (l >= 0 && l < L_)
                v = *(const float4*)(X + (size_t)(g0 + l) * DBERT + c4 * 4);
            f16x4 h = {(_Float16)v.x, (_Float16)v.y, (_Float16)v.z, (_Float16)v.w};
            *(f16x4*)(&As[0][r * APAD + c4 * 4]) = h;
        }
        if (tid < 16) {
            int q = 1024 + tid;
            int r = q >> 3, c4 = q & 7;
            int l = l0 - 1 + r;
            float4 v = make_float4(0.f, 0.f, 0.f, 0.f);
            if (l >= 0 && l < L_)
                v = *(const float4*)(X + (size_t)(g0 + l) * DBERT + c4 * 4);
            f16x4 h = {(_Float16)v.x, (_Float16)v.y, (_Float16)v.z, (_Float16)v.w};
            *(f16x4*)(&As[0][r * APAD + c4 * 4]) = h;
        }
        const uint4* bsrc = (const uint4*)Bp;         // kb=0
        uint4* bdst = (uint4*)&Bs[0][0];
        #pragma unroll
        for (int it = 0; it < 3; ++it) bdst[tid + it * 256] = bsrc[tid + it * 256];
    }
    __syncthreads();

    for (int kb = 0; kb < KSTEPS; ++kb) {
        const int cur = kb & 1, nxt = cur ^ 1;
        const bool have = (kb + 1) < KSTEPS;
        float4 va[5];
        uint4  vb[3];
        if (have) {
            const float* Xk = X + (size_t)(kb + 1) * 32;
            #pragma unroll
            for (int it = 0; it < 4; ++it) {
                int q = tid + it * 256;
                int r = q >> 3, c4 = q & 7;
                int l = l0 - 1 + r;
                va[it] = make_float4(0.f, 0.f, 0.f, 0.f);
                if (l >= 0 && l < L_)
                    va[it] = *(const float4*)(Xk + (size_t)(g0 + l) * DBERT + c4 * 4);
            }
            if (tid < 16) {
                int q = 1024 + tid;
                int r = q >> 3, c4 = q & 7;
                int l = l0 - 1 + r;
                va[4] = make_float4(0.f, 0.f, 0.f, 0.f);
                if (l >= 0 && l < L_)
                    va[4] = *(const float4*)(Xk + (size_t)(g0 + l) * DBERT + c4 * 4);
            }
            const uint4* bsrc = (const uint4*)(Bp + (size_t)(kb + 1) * 6144);
            #pragma unroll
            for (int it = 0; it < 3; ++it) vb[it] = bsrc[tid + it * 256];
        }

        // ---- compute on cur
        f16x8 bfr[3][4];
        #pragma unroll
        for (int t = 0; t < 3; ++t)
            #pragma unroll
            for (int nf = 0; nf < 4; ++nf)
                bfr[t][nf] = *(const f16x8*)(&Bs[cur][(((t * 4 + nf) * 64) + lane) * 8]);
        f16x8 afr[2][3];
        #pragma unroll
        for (int mf = 0; mf < 2; ++mf)
            #pragma unroll
            for (int t = 0; t < 3; ++t)
                afr[mf][t] = *(const f16x8*)(
                    &As[cur][(wv * 32 + mf * 16 + (lane & 15) + t) * APAD + ((lane >> 4) << 3)]);
        #pragma unroll
        for (int mf = 0; mf < 2; ++mf)
            #pragma unroll
            for (int nf = 0; nf < 4; ++nf)
                #pragma unroll
                for (int t = 0; t < 3; ++t)
                    acc[mf][nf] = __builtin_amdgcn_mfma_f32_16x16x32_f16(
                        afr[mf][t], bfr[t][nf], acc[mf][nf], 0, 0, 0);

        // ---- write staged data for kb+1 into nxt
        if (have) {
            #pragma unroll
            for (int it = 0; it < 4; ++it) {
                int q = tid + it * 256;
                int r = q >> 3, c4 = q & 7;
                f16x4 h = {(_Float16)va[it].x, (_Float16)va[it].y,
                           (_Float16)va[it].z, (_Float16)va[it].w};
                *(f16x4*)(&As[nxt][r * APAD + c4 * 4]) = h;
            }
            if (tid < 16) {
                int q = 1024 + tid;
                int r = q >> 3, c4 = q & 7;
                f16x4 h = {(_Float16)va[4].x, (_Float16)va[4].y,
                           (_Float16)va[4].z, (_Float16)va[4].w};
                *(f16x4*)(&As[nxt][r * APAD + c4 * 4]) = h;
            }
            uint4* bdst = (uint4*)&Bs[nxt][0];
            #pragma unroll
            for (int it = 0; it < 3; ++it) bdst[tid + it * 256] = vb[it];
        }
        __syncthreads();
    }

    // ---- epilogue: bias + store fp32  (C layout: col=lane&15, row=(lane>>4)*4+i)
    #pragma unroll
    for (int mf = 0; mf < 2; ++mf)
        #pragma unroll
        for (int nf = 0; nf < 4; ++nf) {
            int col = nf * 16 + (lane & 15);
            float bias = cb[col];
            #pragma unroll
            for (int i = 0; i < 4; ++i) {
                int row = m0 + wv * 32 + mf * 16 + ((lane >> 4) << 2) + i;
                Y[(size_t)row * DPROJ + col] = acc[mf][nf][i] + bias;
            }
        }
}

// One block per batch element: logits -> per-span masked softmax -> weighted
// sum -> BN1 -> fc(192->512) -> ReLU -> BN2 -> concat -> last(529->3).
__global__ __launch_bounds__(256)
void span_mlp_kernel(const float* __restrict__ conv, const int* __restrict__ offs,
                     const float* __restrict__ in_urls, const float* __restrict__ other,
                     const float* __restrict__ att_w, const float* __restrict__ att_b,
                     const float* __restrict__ bn1_g, const float* __restrict__ bn1_b,
                     const float* __restrict__ bn1_m, const float* __restrict__ bn1_v,
                     const float* __restrict__ fc_w, const float* __restrict__ fc_b,
                     const float* __restrict__ bn2_g, const float* __restrict__ bn2_b,
                     const float* __restrict__ bn2_m, const float* __restrict__ bn2_v,
                     const float* __restrict__ last_w, const float* __restrict__ last_b,
                     float* __restrict__ out) {
    __shared__ float logits[L_];
    __shared__ float aw[DPROJ];
    __shared__ float red[8];
    __shared__ float emb[NSPANS * DPROJ];
    __shared__ float hbuf[HIDDEN];

    const int b    = blockIdx.x;
    const int tid  = threadIdx.x;
    const int lane = tid & 63;
    const int wv   = tid >> 6;
    const float* cv = conv + (size_t)b * L_ * DPROJ;

    if (tid < DPROJ) aw[tid] = att_w[tid];
    __syncthreads();

    const float ab = att_b[0];
    for (int l = tid; l < L_; l += 256) {
        const float* row = cv + l * DPROJ;
        float s = ab;
        #pragma unroll 16
        for (int i = 0; i < DPROJ; ++i) s += row[i] * aw[i];
        logits[l] = s;
    }
    __syncthreads();

    for (int sp = 0; sp < NSPANS; ++sp) {
        const int st = offs[b * (NSPANS * 2) + sp * 2 + 0];
        const int en = offs[b * (NSPANS * 2) + sp * 2 + 1];   // inclusive

        float mx = -1e30f;
        for (int l = st + tid; l <= en; l += 256) mx = fmaxf(mx, logits[l]);
        #pragma unroll
        for (int off = 32; off >= 1; off >>= 1) mx = fmaxf(mx, __shfl_xor(mx, off));
        if (lane == 0) red[wv] = mx;
        __syncthreads();
        mx = fmaxf(fmaxf(red[0], red[1]), fmaxf(red[2], red[3]));
        __syncthreads();

        float sm = 0.f;
        for (int l = st + tid; l <= en; l += 256) sm += __expf(logits[l] - mx);
        #pragma unroll
        for (int off = 32; off >= 1; off >>= 1) sm += __shfl_xor(sm, off);
        if (lane == 0) red[wv] = sm;
        __syncthreads();
        const float denom = red[0] + red[1] + red[2] + red[3];

        float a = 0.f;
        for (int l = st + wv; l <= en; l += 4)
            a += __expf(logits[l] - mx) * cv[l * DPROJ + lane];
        hbuf[tid] = a;                                  // scratch reuse
        __syncthreads();
        if (tid < DPROJ)
            emb[sp * DPROJ + tid] =
                (hbuf[tid] + hbuf[64 + tid] + hbuf[128 + tid] + hbuf[192 + tid]) / denom;
        __syncthreads();
    }

    // BN1 in place on extracted[192]
    for (int i = tid; i < NSPANS * DPROJ; i += 256)
        emb[i] = (emb[i] - bn1_m[i]) * rsqrtf(bn1_v[i] + 1e-5f) * bn1_g[i] + bn1_b[i];
    __syncthreads();

    // fc + ReLU + BN2 (wave-coalesced: lane-parallel over the 192 inputs)
    for (int jj = 0; jj < HIDDEN / 4; ++jj) {
        const int j = wv * (HIDDEN / 4) + jj;
        const float* wrow = fc_w + (size_t)j * (NSPANS * DPROJ);
        float s = wrow[lane] * emb[lane] + wrow[64 + lane] * emb[64 + lane] +
                  wrow[128 + lane] * emb[128 + lane];
        #pragma unroll
        for (int off = 32; off >= 1; off >>= 1) s += __shfl_xor(s, off);
        if (lane == 0) {
            s += fc_b[j];
            s = fmaxf(s, 0.f);
            hbuf[j] = (s - bn2_m[j]) * rsqrtf(bn2_v[j] + 1e-5f) * bn2_g[j] + bn2_b[j];
        }
    }
    __syncthreads();

    if (tid < 3) {
        const float* lw = last_w + tid * (HIDDEN + 17);
        float s = last_b[tid];
        for (int i = 0; i < HIDDEN; ++i) s += lw[i] * hbuf[i];
        s += lw[512] * in_urls[b * 3 + 0] + lw[513] * in_urls[b * 3 + 1] +
             lw[514] * in_urls[b * 3 + 2];
        #pragma unroll
        for (int i = 0; i < 14; ++i) s += lw[515 + i] * other[b * 14 + i];
        out[b * 3 + tid] = s;
    }
}

extern "C" void kernel_launch(void* const* d_in, const int* in_sizes, int n_in,
                              void* d_out, int out_size, void* d_ws, size_t ws_size,
                              hipStream_t stream) {
    const float* bert    = (const float*)d_in[0];
    const int*   offs    = (const int*)d_in[1];
    const float* in_urls = (const float*)d_in[2];
    const float* other   = (const float*)d_in[3];
    const float* conv_w  = (const float*)d_in[4];
    const float* conv_b  = (const float*)d_in[5];
    const float* att_w   = (const float*)d_in[6];
    const float* att_b   = (const float*)d_in[7];
    const float* bn1_g   = (const float*)d_in[8];
    const float* bn1_b   = (const float*)d_in[9];
    const float* bn1_m   = (const float*)d_in[10];
    const float* bn1_v   = (const float*)d_in[11];
    const float* fc_w    = (const float*)d_in[12];
    const float* fc_b    = (const float*)d_in[13];
    const float* bn2_g   = (const float*)d_in[14];
    const float* bn2_b   = (const float*)d_in[15];
    const float* bn2_m   = (const float*)d_in[16];
    const float* bn2_v   = (const float*)d_in[17];
    const float* last_w  = (const float*)d_in[18];
    const float* last_b  = (const float*)d_in[19];

    // ws layout: [0, 393216): packed f16 weights; [393216, +16.78MB): conv_out
    _Float16* Bp     = (_Float16*)d_ws;
    float*    convout = (float*)((char*)d_ws + 393216);

    hipLaunchKernelGGL(pack_w_kernel, dim3(96), dim3(256), 0, stream, conv_w, Bp);
    hipLaunchKernelGGL(conv_gemm_kernel, dim3((B_ * L_) / 128), dim3(256), 0, stream,
                       bert, Bp, conv_b, convout);
    hipLaunchKernelGGL(span_mlp_kernel, dim3(B_), dim3(256), 0, stream,
                       convout, offs, in_urls, other, att_w, att_b,
                       bn1_g, bn1_b, bn1_m, bn1_v, fc_w, fc_b,
                       bn2_g, bn2_b, bn2_m, bn2_v, last_w, last_b,
                       (float*)d_out);
}